// Round 6
// baseline (2675.883 us; speedup 1.0000x reference)
//
#include <hip/hip_runtime.h>
#include <hip/hip_bf16.h>
#include <math.h>

#define LSEQ 256
#define BB   64
#define EE   256
#define HH   256

// ---------------- embedding gather: x0[r][e] = emb[tokens[r]][e] ----------------
__global__ __launch_bounds__(64)
void embed_kernel(const int* __restrict__ tokens, const float* __restrict__ emb,
                  float* __restrict__ x0) {
    int r = blockIdx.x;
    int tok = tokens[r];
    const float4* src = (const float4*)(emb + (size_t)tok * EE);
    float4* dst = (float4*)(x0 + (size_t)r * EE);
    dst[threadIdx.x] = src[threadIdx.x];
}

// ---- pack W_hh into W3[ld][ut(16)][k(256)][c(64)], c = g*16+ul, src w[(g*256+ut*16+ul)][k] ----
__global__ __launch_bounds__(256)
void pack_w3_kernel(const float* __restrict__ w0, const float* __restrict__ w1,
                    const float* __restrict__ w2, const float* __restrict__ w3,
                    float* __restrict__ W3) {
    __shared__ float t[16][65];
    const float* w = blockIdx.z == 0 ? w0 : blockIdx.z == 1 ? w1 : blockIdx.z == 2 ? w2 : w3;
    float* out = W3 + (size_t)blockIdx.z * 262144;
    int ut = blockIdx.y;
    int g = blockIdx.x >> 2, kt = blockIdx.x & 3;
    int k0 = kt * 64, tid = threadIdx.x;
    for (int e = tid; e < 1024; e += 256) {
        int ul = e >> 6, kl = e & 63;
        t[ul][kl] = w[(size_t)(g * 256 + ut * 16 + ul) * 256 + k0 + kl];
    }
    __syncthreads();
    for (int e = tid; e < 1024; e += 256) {
        int kl = e >> 4, ul = e & 15;
        out[(size_t)(ut * 256 + k0 + kl) * 64 + g * 16 + ul] = t[ul][kl];
    }
}

// ---------------- C[M,N] = A[M,K] @ W[N,K]^T + b1[N] + b2[N] ----------------
__global__ __launch_bounds__(256)
void gemm_bias_kernel(const float* __restrict__ A, const float* __restrict__ W,
                      const float* __restrict__ b1, const float* __restrict__ b2,
                      float* __restrict__ C, int M, int N, int K) {
    const int BK = 16;
    __shared__ float As[BK][128];
    __shared__ float Bs[BK][128];
    int tid = threadIdx.x;
    int bm = blockIdx.x * 128;
    int bn = blockIdx.y * 128;
    int tm = (tid >> 4) << 3;
    int tn = (tid & 15) << 3;
    int lr = tid >> 1;
    int lc = (tid & 1) << 3;
    const float* Ap = A + (size_t)(bm + lr) * K + lc;
    const float* Wpt = W + (size_t)(bn + lr) * K + lc;
    float acc[8][8];
#pragma unroll
    for (int i = 0; i < 8; i++)
#pragma unroll
        for (int j = 0; j < 8; j++) acc[i][j] = 0.f;

    for (int k0 = 0; k0 < K; k0 += BK) {
        float4 a0 = *(const float4*)(Ap + k0);
        float4 a1 = *(const float4*)(Ap + k0 + 4);
        float4 w0 = *(const float4*)(Wpt + k0);
        float4 w1 = *(const float4*)(Wpt + k0 + 4);
        __syncthreads();
        As[lc+0][lr]=a0.x; As[lc+1][lr]=a0.y; As[lc+2][lr]=a0.z; As[lc+3][lr]=a0.w;
        As[lc+4][lr]=a1.x; As[lc+5][lr]=a1.y; As[lc+6][lr]=a1.z; As[lc+7][lr]=a1.w;
        Bs[lc+0][lr]=w0.x; Bs[lc+1][lr]=w0.y; Bs[lc+2][lr]=w0.z; Bs[lc+3][lr]=w0.w;
        Bs[lc+4][lr]=w1.x; Bs[lc+5][lr]=w1.y; Bs[lc+6][lr]=w1.z; Bs[lc+7][lr]=w1.w;
        __syncthreads();
#pragma unroll
        for (int k = 0; k < BK; k++) {
            float av[8], bv[8];
            *(float4*)&av[0] = *(const float4*)&As[k][tm];
            *(float4*)&av[4] = *(const float4*)&As[k][tm+4];
            *(float4*)&bv[0] = *(const float4*)&Bs[k][tn];
            *(float4*)&bv[4] = *(const float4*)&Bs[k][tn+4];
#pragma unroll
            for (int i = 0; i < 8; i++)
#pragma unroll
                for (int j = 0; j < 8; j++) acc[i][j] = fmaf(av[i], bv[j], acc[i][j]);
        }
    }
    float bj[8];
#pragma unroll
    for (int j = 0; j < 8; j++) bj[j] = b1[bn+tn+j] + b2[bn+tn+j];
#pragma unroll
    for (int i = 0; i < 8; i++) {
        float4 v0, v1;
        v0.x = acc[i][0]+bj[0]; v0.y = acc[i][1]+bj[1]; v0.z = acc[i][2]+bj[2]; v0.w = acc[i][3]+bj[3];
        v1.x = acc[i][4]+bj[4]; v1.y = acc[i][5]+bj[5]; v1.z = acc[i][6]+bj[6]; v1.w = acc[i][7]+bj[7];
        *(float4*)&C[(size_t)(bm+tm+i)*N + bn+tn]     = v0;
        *(float4*)&C[(size_t)(bm+tm+i)*N + bn+tn + 4] = v1;
    }
}

// ---------------- LSTM scan: tagged-payload exchange (single-hop sync) ----------------
// 256 blocks = 16 domains (dom = bid&15: dir = dom&1, batch-tile bt = dom>>1, 8 seqs)
//            x 16 unit-blocks (ut = bid>>4, 16 units each).
// Exchange: h published as 64-bit atom (tag<<32 | float bits) via atomicExch;
// consumers poll the data lines with relaxed agent-scope 64-bit atomic loads until
// tag == base+s (load/RMW coherence pair proven in rounds 4-5). No counters, no
// fences, no vmcnt drains: ONE L2 hop producer->consumer. Parity-2 buffer; WAR-safe
// by the transitive publish-after-consume argument. Tags disjoint across scans and
// graph replays (base 1 / 257; stale tags and 0xAA poison can never match).
__global__ __launch_bounds__(256, 1)
void lstm_scan_kernel(const float* __restrict__ Gf, const float* __restrict__ Gb,
                      const float* __restrict__ W3f, const float* __restrict__ W3b,
                      const int* __restrict__ lengths, float* __restrict__ xout,
                      unsigned long long* __restrict__ hg, int tagbase) {
    const int bid = blockIdx.x;
    const int dom = bid & 15;
    const int ut  = bid >> 4;
    const int dir = dom & 1;
    const int bt  = dom >> 1;                      // 0..7, 8 sequences each
    const float* __restrict__ G = dir ? Gb : Gf;
    const float* __restrict__ W3 = (dir ? W3b : W3f) + (size_t)ut * 16384;
    unsigned long long* hgD = hg + (size_t)dom * 4096;   // [2 parity][8 b][256 u]

    __shared__ float hs[2048];                     // h(s-1): [8 b][256 u]
    __shared__ float P[4096];                      // [8 kg][8 b][64 c], xor-swizzled
    __shared__ float lds_pad[16384];               // force 1 block/CU

    const int tid = threadIdx.x;
    const int kg = tid >> 5;                       // 0..7  : k-slice of 32
    const int cw = tid & 31;                       // 0..31 : col pair c = 2cw, 2cw+1
    const int cb = (tid >> 4) & 7;                 // combine batch row (tid<128)
    const int cu = tid & 15;                       // combine unit-local
    const int bg = bt * 8 + cb;
    const int ug = ut * 16 + cu;
    const int mylen = lengths[bg];

    // W registers: wreg[kk] = W3[kg*32+kk][2cw .. 2cw+1]
    float2 wreg[32];
#pragma unroll
    for (int kk = 0; kk < 32; kk++)
        wreg[kk] = *(const float2*)&W3[(size_t)(kg * 32 + kk) * 64 + cw * 2];

#pragma unroll
    for (int i = 0; i < 2; i++)
        *(float4*)&hs[(tid + 256 * i) * 4] = make_float4(0.f, 0.f, 0.f, 0.f);
    if (tid == 0 && mylen < 0) lds_pad[0] = 1.f;   // keep pad live (mylen >= 128 always)

    float cstate = 0.f;
    int tcur = dir ? (mylen - 1) : 0;
    const float* gr0 = G + ((size_t)tcur * BB + bg) * 1024 + ug;
    float gp0 = gr0[0], gp1 = gr0[256], gp2 = gr0[512], gp3 = gr0[768];
    __syncthreads();

    for (int s = 0; s < LSEQ; s++) {
        if (s > 0) {
            // ---- stage h(s-1): poll the tagged data lines directly ----
            const unsigned exp = (unsigned)(tagbase + s - 1);
            const unsigned long long* src = hgD + ((s - 1) & 1) * 2048;
            unsigned long long v[8];
#pragma unroll
            for (int i = 0; i < 8; i++)
                v[i] = __hip_atomic_load(src + tid + 256 * i, __ATOMIC_RELAXED,
                                         __HIP_MEMORY_SCOPE_AGENT);
            for (;;) {
                bool ok = true;
#pragma unroll
                for (int i = 0; i < 8; i++) ok &= ((unsigned)(v[i] >> 32) == exp);
                if (ok) break;
#pragma unroll
                for (int i = 0; i < 8; i++)
                    if ((unsigned)(v[i] >> 32) != exp)
                        v[i] = __hip_atomic_load(src + tid + 256 * i, __ATOMIC_RELAXED,
                                                 __HIP_MEMORY_SCOPE_AGENT);
            }
#pragma unroll
            for (int i = 0; i < 8; i++)
                hs[tid + 256 * i] = __uint_as_float((unsigned)v[i]);
            __syncthreads();
        }

        // ---- FMA phase: acc[b] (2 cols) partial over k in [kg*32, kg*32+32) ----
        float2 acc[8];
        const float4* h4 = (const float4*)hs;
#pragma unroll
        for (int b = 0; b < 8; b++) {
            float2 a = make_float2(0.f, 0.f);
            int hbase = b * 64 + kg * 8;
#pragma unroll
            for (int q = 0; q < 8; q++) {
                float4 hv = h4[hbase + q];
                a.x = fmaf(wreg[q*4+0].x, hv.x, a.x); a.y = fmaf(wreg[q*4+0].y, hv.x, a.y);
                a.x = fmaf(wreg[q*4+1].x, hv.y, a.x); a.y = fmaf(wreg[q*4+1].y, hv.y, a.y);
                a.x = fmaf(wreg[q*4+2].x, hv.z, a.x); a.y = fmaf(wreg[q*4+2].y, hv.z, a.y);
                a.x = fmaf(wreg[q*4+3].x, hv.w, a.x); a.y = fmaf(wreg[q*4+3].y, hv.w, a.y);
            }
            acc[b] = a;
        }
        const int wofs = (cw * 2) ^ (kg * 2);
#pragma unroll
        for (int b = 0; b < 8; b++)
            *(float2*)&P[kg * 512 + b * 64 + wofs] = acc[b];
        __syncthreads();

        if (tid < 128) {
            // ---- combine: thread (cb, cu) sums 8 kg-partials for its 4 gates ----
            float g0 = gp0, g1 = gp1, g2 = gp2, g3 = gp3;
#pragma unroll
            for (int k2 = 0; k2 < 8; k2++) {
                int base = k2 * 512 + cb * 64;
                int x = k2 * 2;
                g0 += P[base + ((cu)      ^ x)];
                g1 += P[base + ((16 + cu) ^ x)];
                g2 += P[base + ((32 + cu) ^ x)];
                g3 += P[base + ((48 + cu) ^ x)];
            }
            float iv = 1.f / (1.f + expf(-g0));
            float fv = 1.f / (1.f + expf(-g1));
            float gv = tanhf(g2);
            float ov = 1.f / (1.f + expf(-g3));
            cstate = fv * cstate + iv * gv;
            float h = ov * tanhf(cstate);
            // publish: tag + payload in one 64-bit atom (fire-and-forget)
            unsigned long long pv =
                ((unsigned long long)(unsigned)(tagbase + s) << 32) | __float_as_uint(h);
            atomicExch(&hgD[(s & 1) * 2048 + cb * 256 + ug], pv);
            xout[(size_t)(tcur * BB + bg) * 512 + dir * 256 + ug] = (s < mylen) ? h : 0.f;
            if (s < 255) {                                          // G prefetch under poll
                int s2 = s + 1;
                tcur = dir ? (s2 < mylen ? mylen - 1 - s2 : s2) : s2;
                const float* gr = G + ((size_t)tcur * BB + bg) * 1024 + ug;
                gp0 = gr[0]; gp1 = gr[256]; gp2 = gr[512]; gp3 = gr[768];
            }
        }
    }
}

// ---------------- emissions: em[r][n] = x[r]·w_out[n] + b_out[n] ----------------
__global__ __launch_bounds__(256)
void emis_kernel(const float* __restrict__ x, const float* __restrict__ w_out,
                 const float* __restrict__ b_out, float* __restrict__ em) {
    __shared__ float ws_[16][516];
    __shared__ float xs[16][516];
    int tid = threadIdx.x;
    size_t r0 = (size_t)blockIdx.x * 16;
    for (int i4 = tid; i4 < 2048; i4 += 256) {
        int r = i4 >> 7, k4 = (i4 & 127) << 2;
        *(float4*)&ws_[r][k4] = *(const float4*)&w_out[r*512 + k4];
        *(float4*)&xs[r][k4]  = *(const float4*)&x[(r0 + r)*512 + k4];
    }
    __syncthreads();
    int rr = tid >> 4, n = tid & 15;
    const float4* xr = (const float4*)&xs[rr][0];
    const float4* wr = (const float4*)&ws_[n][0];
    float4 s; s.x = s.y = s.z = s.w = 0.f;
#pragma unroll 8
    for (int k = 0; k < 128; k++) {
        float4 a = xr[k], b = wr[k];
        s.x = fmaf(a.x,b.x,s.x); s.y = fmaf(a.y,b.y,s.y);
        s.z = fmaf(a.z,b.z,s.z); s.w = fmaf(a.w,b.w,s.w);
    }
    em[(r0+rr)*16 + n] = s.x+s.y+s.z+s.w + b_out[n];
}

// ---------------- CRF Viterbi decode, one block per batch element ----------------
__global__ __launch_bounds__(64)
void viterbi_kernel(const float* __restrict__ em, const int* __restrict__ tokens,
                    const float* __restrict__ start_trans, const float* __restrict__ end_trans,
                    const float* __restrict__ trans, float* __restrict__ out) {
    __shared__ float em_s[256][16];
    __shared__ float tr_s[16][16];
    __shared__ float sc[16];
    __shared__ unsigned char hist[255][16];
    int b = blockIdx.x, tid = threadIdx.x;
    for (int i = tid; i < 4096; i += 64) {
        int t = i >> 4, n = i & 15;
        em_s[t][n] = em[(size_t)t*1024 + b*16 + n];
    }
    for (int i = tid; i < 256; i += 64) ((float*)tr_s)[i] = trans[i];
    __syncthreads();
    if (tid < 16) sc[tid] = start_trans[tid] + em_s[0][tid];
    __syncthreads();
    for (int t = 1; t < 256; t++) {
        float best = 0.f; int arg = 0;
        if (tid < 16) {
            best = sc[0] + tr_s[0][tid];
#pragma unroll
            for (int i = 1; i < 16; i++) {
                float v = sc[i] + tr_s[i][tid];
                if (v > best) { best = v; arg = i; }
            }
            best += em_s[t][tid];
            hist[t-1][tid] = (unsigned char)arg;
        }
        bool m = tokens[t*64 + b] != 0;
        __syncthreads();
        if (tid < 16 && m) sc[tid] = best;
        __syncthreads();
    }
    if (tid == 0) {
        float best = sc[0] + end_trans[0]; int cur = 0;
        for (int jj = 1; jj < 16; jj++) {
            float v = sc[jj] + end_trans[jj];
            if (v > best) { best = v; cur = jj; }
        }
        out[b] = best;
        float* tags = out + 64;
        tags[255*64 + b] = (tokens[255*64+b] != 0) ? (float)cur : 0.f;
        for (int t = 254; t >= 0; t--) {
            if (tokens[(t+1)*64 + b] != 0) cur = hist[t][cur];
            tags[t*64 + b] = (tokens[t*64+b] != 0) ? (float)cur : 0.f;
        }
    }
}

extern "C" void kernel_launch(void* const* d_in, const int* in_sizes, int n_in,
                              void* d_out, int out_size, void* d_ws, size_t ws_size,
                              hipStream_t stream) {
    const int*   tokens   = (const int*)d_in[0];
    const int*   lengths  = (const int*)d_in[1];
    const float* emb      = (const float*)d_in[2];
    const float* w_ih_l0f = (const float*)d_in[3];
    const float* w_hh_l0f = (const float*)d_in[4];
    const float* b_ih_l0f = (const float*)d_in[5];
    const float* b_hh_l0f = (const float*)d_in[6];
    const float* w_ih_l0b = (const float*)d_in[7];
    const float* w_hh_l0b = (const float*)d_in[8];
    const float* b_ih_l0b = (const float*)d_in[9];
    const float* b_hh_l0b = (const float*)d_in[10];
    const float* w_ih_l1f = (const float*)d_in[11];
    const float* w_hh_l1f = (const float*)d_in[12];
    const float* b_ih_l1f = (const float*)d_in[13];
    const float* b_hh_l1f = (const float*)d_in[14];
    const float* w_ih_l1b = (const float*)d_in[15];
    const float* w_hh_l1b = (const float*)d_in[16];
    const float* b_ih_l1b = (const float*)d_in[17];
    const float* b_hh_l1b = (const float*)d_in[18];
    const float* w_out    = (const float*)d_in[19];
    const float* b_out    = (const float*)d_in[20];
    const float* start_tr = (const float*)d_in[21];
    const float* end_tr   = (const float*)d_in[22];
    const float* trans    = (const float*)d_in[23];

    // workspace layout (floats)
    float* ws  = (float*)d_ws;
    float* x0  = ws;                       // [16384][256]  (later: em + hg overlays)
    float* x1  = x0 + 4194304;             // [16384][512]
    float* x2  = x1 + 8388608;             // [16384][512]
    float* Gf  = x2 + 8388608;             // [16384][1024]
    float* Gb  = Gf + 16777216;            // [16384][1024]
    float* W3  = Gb + 16777216;            // 4 x [16][256][64] packed W_hh
    float* W3l0f = W3, *W3l0b = W3 + 262144, *W3l1f = W3 + 524288, *W3l1b = W3 + 786432;
    float* em  = x0;                       // [16384][16], reuse x0 after layer-0 GEMMs
    unsigned long long* hg = (unsigned long long*)(x0 + 1048576); // [16 dom][2 par][2048] u64

    embed_kernel<<<16384, 64, 0, stream>>>(tokens, emb, x0);
    pack_w3_kernel<<<dim3(16, 16, 4), 256, 0, stream>>>(w_hh_l0f, w_hh_l0b, w_hh_l1f, w_hh_l1b, W3);

    dim3 gg(128, 8);
    gemm_bias_kernel<<<gg, 256, 0, stream>>>(x0, w_ih_l0f, b_ih_l0f, b_hh_l0f, Gf, 16384, 1024, 256);
    gemm_bias_kernel<<<gg, 256, 0, stream>>>(x0, w_ih_l0b, b_ih_l0b, b_hh_l0b, Gb, 16384, 1024, 256);
    lstm_scan_kernel<<<256, 256, 0, stream>>>(Gf, Gb, W3l0f, W3l0b, lengths, x1, hg, 1);

    gemm_bias_kernel<<<gg, 256, 0, stream>>>(x1, w_ih_l1f, b_ih_l1f, b_hh_l1f, Gf, 16384, 1024, 512);
    gemm_bias_kernel<<<gg, 256, 0, stream>>>(x1, w_ih_l1b, b_ih_l1b, b_hh_l1b, Gb, 16384, 1024, 512);
    lstm_scan_kernel<<<256, 256, 0, stream>>>(Gf, Gb, W3l1f, W3l1b, lengths, x2, hg, 257);

    emis_kernel<<<1024, 256, 0, stream>>>(x2, w_out, b_out, em);
    viterbi_kernel<<<64, 64, 0, stream>>>(em, tokens, start_tr, end_tr, trans, (float*)d_out);
}